// Round 4
// baseline (255.141 us; speedup 1.0000x reference)
//
#include <hip/hip_runtime.h>
#include <hip/hip_bf16.h>
#include <math.h>

// ---------------------------------------------------------------------------
// SE3 warping field: nerf_encode -> 6-layer MLP (skip@4) -> heads -> se3 exp
// Round 4: register-resident activations (shfl redistribution between layers),
// W staged to LDS via async global_load_lds (double-buffered, 1 barrier/layer),
// 8 waves x 64 rows per block, full-m per wave.
// ---------------------------------------------------------------------------

typedef __bf16 bf16x8 __attribute__((ext_vector_type(8)));
typedef float  f32x4  __attribute__((ext_vector_type(4)));
typedef unsigned uintx4 __attribute__((ext_vector_type(4)));

#define NROWS 524288
#define BROWS 512

// packed-weight offsets in bf16 elements: frag layout [mf][s][lane][j],
// value = W[m = 16mf + (lane&15)][k = 32s + 8(lane>>4) + j]  (PROVEN r1-r3)
#define P0 0        // L0: K=64  (53 padded)      16 frags
#define P1 8192     // L1: K=128                  32 frags
#define P2 24576
#define P3 40960
#define P4 57344    // L4: K=192 (53+pad11 | 128) 48 frags
#define P5 81920
#define PH 98304    // head: m 0..2=Wv, 3..5=Wr, rest 0 ; 4 frags
#define PTOT 100352

// LDS byte offsets
#define WA_OFF   0        // 48 KiB weight buffer A (L0, L2, L4, head)
#define WB_OFF   49152    // 32 KiB weight buffer B (L1, L3, L5)
#define X0_OFF   81920    // 64 KiB encoded input [512 rows][128 B], swizzled
#define BIAS_OFF 147456   // 3.2 KiB biases (6*128 + 32 floats)
#define SCREW_OFF 49152   // screw [512][32 B] (aliases WB; dead at head phase)
#define LDS_SZ   150784

// ---------------------------------------------------------------------------
template<int KS, int FAN>
__device__ __forceinline__ float pack_val(const float* __restrict__ W, int idx)
{
    int f  = idx / (KS * 512);
    int r2 = idx % (KS * 512);
    int s  = r2 >> 9, r3 = r2 & 511, ln = r3 >> 3, j = r3 & 7;
    int col = f * 16 + (ln & 15);
    int k   = s * 32 + (ln >> 4) * 8 + j;
    if (FAN == 128) return W[col * 128 + k];
    if (FAN == 53)  return (k < 53) ? W[col * 53 + k] : 0.f;
    if (k < 53)  return W[col * 181 + k];
    if (k < 64)  return 0.f;
    return W[col * 181 + (k - 11)];
}

__global__ void pack_w(const float* __restrict__ W0, const float* __restrict__ W1,
                       const float* __restrict__ W2, const float* __restrict__ W3,
                       const float* __restrict__ W4, const float* __restrict__ W5,
                       const float* __restrict__ Wr, const float* __restrict__ Wv,
                       __bf16* __restrict__ pk)
{
    int e = blockIdx.x * 256 + threadIdx.x;
    if (e >= PTOT) return;
    float val;
    if (e >= PH) {
        int rem = e - PH;
        int s = rem >> 9, r3 = rem & 511, ln = r3 >> 3, j = r3 & 7;
        int col = ln & 15;
        int k = s * 32 + (ln >> 4) * 8 + j;
        if (col < 3)      val = Wv[col * 128 + k];
        else if (col < 6) val = Wr[(col - 3) * 128 + k];
        else              val = 0.f;
    }
    else if (e < P1) val = pack_val<2, 53 >(W0, e - P0);
    else if (e < P2) val = pack_val<4, 128>(W1, e - P1);
    else if (e < P3) val = pack_val<4, 128>(W2, e - P2);
    else if (e < P4) val = pack_val<4, 128>(W3, e - P3);
    else if (e < P5) val = pack_val<6, 181>(W4, e - P4);
    else             val = pack_val<4, 128>(W5, e - P5);
    pk[e] = (__bf16)val;
}

// ---------------------------------------------------------------------------
__device__ __forceinline__ unsigned pack_bf16_2(float a, float b) {
    union { __bf16 h; unsigned short u; } x, y;
    x.h = (__bf16)a; y.h = (__bf16)b;
    return ((unsigned)y.u << 16) | (unsigned)x.u;
}

__device__ __forceinline__ void gload_lds16(const __bf16* g, unsigned char* l) {
    __builtin_amdgcn_global_load_lds(
        (const __attribute__((address_space(1))) unsigned int*)g,
        (__attribute__((address_space(3))) unsigned int*)l, 16, 0, 0);
}

// stage nfrags 1KB fragments of packed W into LDS (linear, conflict-free)
__device__ __forceinline__ void stageW(const __bf16* __restrict__ pkL,
                                       unsigned char* wdst, int nfrags,
                                       int w, int lane) {
    for (int f = w; f < nfrags; f += 8)
        gload_lds16(pkL + f * 512 + lane * 8, wdst + f * 1024);
}

// ---------------------------------------------------------------------------
// One MLP layer. Wave owns rows [64w, 64w+64) (nf=0..3), all 128 out-cols
// (mf=0..7). A = W (from LDS), B = activations (X regs, or X0 LDS for the
// first SPLIT k-steps). Output: relu -> bf16 pack -> shfl redistribution
// into X as next layer's B-fragments.
template<int KS, int SPLIT>
__device__ __forceinline__ void layer16(
    unsigned char* smem, int wOff, int lyr,
    const __bf16* __restrict__ pkNext, int nFragsNext, int wOffNext,
    uintx4 (&X)[4][4],
    int w, int lane, int c, int g, int sA, int sB, int hiG)
{
    f32x4 acc[8][4];
    #pragma unroll
    for (int mf = 0; mf < 8; mf++) {
        f32x4 bb = *(const f32x4*)(smem + BIAS_OFF + (lyr * 128 + mf * 16 + g * 4) * 4);
        #pragma unroll
        for (int nf = 0; nf < 4; nf++) acc[mf][nf] = bb;
    }

    // async stage of next layer's W into the other buffer (full layer of slack)
    stageW(pkNext, smem + wOffNext, nFragsNext, w, lane);

    #pragma unroll
    for (int s = 0; s < KS; s++) {
        bf16x8 Bf[4];
        #pragma unroll
        for (int nf = 0; nf < 4; nf++) {
            if (s < SPLIT) {
                int row = 64 * w + nf * 16 + c;
                Bf[nf] = *(const bf16x8*)(smem + X0_OFF + row * 128
                                          + ((64 * s + 16 * g) ^ ((row & 7) << 4)));
            } else {
                Bf[nf] = __builtin_bit_cast(bf16x8, X[(s >= SPLIT) ? s - SPLIT : 0][nf]);
            }
        }
        #pragma unroll
        for (int mf = 0; mf < 8; mf++) {
            bf16x8 Wf = *(const bf16x8*)(smem + wOff + (mf * KS + s) * 1024 + lane * 16);
            #pragma unroll
            for (int nf = 0; nf < 4; nf++)
                acc[mf][nf] = __builtin_amdgcn_mfma_f32_16x16x32_bf16(
                    Wf, Bf[nf], acc[mf][nf], 0, 0, 0);
        }
    }

    // epilogue: relu + pack + in-register redistribution.
    // Next-layer B-frag (s,nf) lane (c,g) wants Y[k=32s+8g+j][n=16nf+c]:
    //   mf_src = 2s + (g>>1); g_src = 2(g&1) + (j>>2); r = j&3.
    #pragma unroll
    for (int nf = 0; nf < 4; nf++) {
        unsigned lo[8], hi[8];
        #pragma unroll
        for (int mf = 0; mf < 8; mf++) {
            f32x4 a = acc[mf][nf];
            lo[mf] = pack_bf16_2(fmaxf(a[0], 0.f), fmaxf(a[1], 0.f));
            hi[mf] = pack_bf16_2(fmaxf(a[2], 0.f), fmaxf(a[3], 0.f));
        }
        #pragma unroll
        for (int s = 0; s < 4; s++) {
            unsigned e0 = (unsigned)__shfl((int)lo[2*s],   sA, 64);
            unsigned e1 = (unsigned)__shfl((int)lo[2*s+1], sA, 64);
            unsigned f0 = (unsigned)__shfl((int)hi[2*s],   sA, 64);
            unsigned f1 = (unsigned)__shfl((int)hi[2*s+1], sA, 64);
            unsigned e2 = (unsigned)__shfl((int)lo[2*s],   sB, 64);
            unsigned e3 = (unsigned)__shfl((int)lo[2*s+1], sB, 64);
            unsigned f2 = (unsigned)__shfl((int)hi[2*s],   sB, 64);
            unsigned f3 = (unsigned)__shfl((int)hi[2*s+1], sB, 64);
            X[s][nf][0] = hiG ? e1 : e0;
            X[s][nf][1] = hiG ? f1 : f0;
            X[s][nf][2] = hiG ? e3 : e2;
            X[s][nf][3] = hiG ? f3 : f2;
        }
    }
    __syncthreads();   // all waves done reading wOff; staged wOffNext complete
}

// ---------------------------------------------------------------------------
__global__ __launch_bounds__(512, 2)
void se3_fused(const float* __restrict__ pos, const float* __restrict__ dir,
               const float* __restrict__ wcode,
               const float* __restrict__ b0, const float* __restrict__ b1,
               const float* __restrict__ b2, const float* __restrict__ b3,
               const float* __restrict__ b4, const float* __restrict__ b5,
               const float* __restrict__ br, const float* __restrict__ bv,
               const __bf16* __restrict__ pk,
               float* __restrict__ out)
{
    __shared__ unsigned char smem[LDS_SZ];
    const int tid  = threadIdx.x;
    const int lane = tid & 63;
    const int w    = tid >> 6;
    const int c    = lane & 15;
    const int g    = lane >> 4;
    const int r0   = blockIdx.x * BROWS;
    const int sA   = c + 32 * (g & 1);
    const int sB   = sA + 16;
    const int hiG  = g >> 1;

    // ---- issue L0 weight staging first (latency hidden under encode) ----
    stageW(pk + P0, smem + WA_OFF, 16, w, lane);

    // ---- stage biases into LDS: [l*128 + m], l=6 is head (32 entries) ----
    if (tid < 800) {
        int l = tid >> 7, m = tid & 127;
        float v;
        if      (l == 0) v = b0[m];
        else if (l == 1) v = b1[m];
        else if (l == 2) v = b2[m];
        else if (l == 3) v = b3[m];
        else if (l == 4) v = b4[m];
        else if (l == 5) v = b5[m];
        else v = (m < 3) ? bv[m] : ((m < 6) ? br[m - 3] : 0.f);
        *(float*)(smem + BIAS_OFF + tid * 4) = v;
    }

    // ---- encode: X0[row][64] = [sin21 | cos21 | p3 | wc8 | 0*11], row=tid --
    {
        int row = tid, gg = r0 + row;
        float p3v[3] = { pos[gg*3+0], pos[gg*3+1], pos[gg*3+2] };
        float vals[64];
        #pragma unroll
        for (int a = 0; a < 3; a++) {
            float p = p3v[a];
            #pragma unroll
            for (int f = 0; f < 7; f++) {
                float t = p * (float)(1 << f);
                t -= floorf(t);
                float ang = 6.283185307179586f * t;
                vals[a*7+f]      = __sinf(ang);
                vals[21+a*7+f]   = __cosf(ang);
            }
        }
        vals[42] = p3v[0]; vals[43] = p3v[1]; vals[44] = p3v[2];
        const float4* wc4 = (const float4*)(wcode + (size_t)gg * 8);
        float4 wa = wc4[0], wb = wc4[1];
        vals[45] = wa.x; vals[46] = wa.y; vals[47] = wa.z; vals[48] = wa.w;
        vals[49] = wb.x; vals[50] = wb.y; vals[51] = wb.z; vals[52] = wb.w;
        #pragma unroll
        for (int q = 53; q < 64; q++) vals[q] = 0.f;

        int sw = (row & 7) << 4;
        unsigned char* base = smem + X0_OFF + row * 128;
        #pragma unroll
        for (int cc = 0; cc < 8; cc++) {
            uintx4 u;
            u[0] = pack_bf16_2(vals[cc*8+0], vals[cc*8+1]);
            u[1] = pack_bf16_2(vals[cc*8+2], vals[cc*8+3]);
            u[2] = pack_bf16_2(vals[cc*8+4], vals[cc*8+5]);
            u[3] = pack_bf16_2(vals[cc*8+6], vals[cc*8+7]);
            *(uintx4*)(base + ((16 * cc) ^ sw)) = u;
        }
    }
    __syncthreads();   // X0 + WA(L0) + biases ready

    // ---- MLP stem (activations register-resident after L0) ----
    uintx4 X[4][4];
    layer16<2,2>(smem, WA_OFF, 0, pk + P1, 32, WB_OFF, X, w, lane, c, g, sA, sB, hiG);
    layer16<4,0>(smem, WB_OFF, 1, pk + P2, 32, WA_OFF, X, w, lane, c, g, sA, sB, hiG);
    layer16<4,0>(smem, WA_OFF, 2, pk + P3, 32, WB_OFF, X, w, lane, c, g, sA, sB, hiG);
    layer16<4,0>(smem, WB_OFF, 3, pk + P4, 48, WA_OFF, X, w, lane, c, g, sA, sB, hiG);
    layer16<6,2>(smem, WA_OFF, 4, pk + P5, 32, WB_OFF, X, w, lane, c, g, sA, sB, hiG); // skip
    layer16<4,0>(smem, WB_OFF, 5, pk + PH,  4, WA_OFF, X, w, lane, c, g, sA, sB, hiG);

    // ---- head: screw = [v(3) | r(3)], one 16-col m-frag, all waves ----
    {
        f32x4 hb = *(const f32x4*)(smem + BIAS_OFF + (768 + g * 4) * 4);
        f32x4 ah[4];
        #pragma unroll
        for (int nf = 0; nf < 4; nf++) ah[nf] = hb;
        #pragma unroll
        for (int s = 0; s < 4; s++) {
            bf16x8 Wh = *(const bf16x8*)(smem + WA_OFF + s * 1024 + lane * 16);
            #pragma unroll
            for (int nf = 0; nf < 4; nf++)
                ah[nf] = __builtin_amdgcn_mfma_f32_16x16x32_bf16(
                    Wh, __builtin_bit_cast(bf16x8, X[s][nf]), ah[nf], 0, 0, 0);
        }
        // screw store: lane (c,g) holds m'=4g+r for row 64w+16nf+c
        #pragma unroll
        for (int nf = 0; nf < 4; nf++) {
            int row = 64 * w + nf * 16 + c;
            if (g == 0) {
                *(f32x4*)(smem + SCREW_OFF + row * 32) = ah[nf];        // v0,v1,v2,w0
            } else if (g == 1) {
                float* sp = (float*)(smem + SCREW_OFF + row * 32);
                sp[4] = ah[nf][0];                                      // w1
                sp[5] = ah[nf][1];                                      // w2
            }
        }
    }
    __syncthreads();

    // ---- se3 exp map epilogue: 1 thread per row (all 512 threads) ----
    {
        int row = tid, gg = r0 + row;
        const float* sc = (const float*)(smem + SCREW_OFF + row * 32);
        float v0 = sc[0], v1 = sc[1], v2 = sc[2];
        float wx = sc[3], wy = sc[4], wz = sc[5];
        float ang2 = wx*wx + wy*wy + wz*wz;
        ang2 = fmaxf(ang2, 1e-4f);               // jnp.clip(.., eps)
        float ang = sqrtf(ang2);
        float sn = __sinf(ang), cs = __cosf(ang);
        float f1 = sn / ang;
        float f2 = (1.f - cs) / ang2;
        float f3 = (ang - sn) / (ang * ang2);
        float K[3][3] = {{0.f,  wz, -wy}, {-wz, 0.f,  wx}, { wy, -wx, 0.f}};
        float KK[3][3];
        #pragma unroll
        for (int i = 0; i < 3; i++)
            #pragma unroll
            for (int j = 0; j < 3; j++)
                KK[i][j] = K[i][0]*K[0][j] + K[i][1]*K[1][j] + K[i][2]*K[2][j];
        float R[3][3], V[3][3];
        #pragma unroll
        for (int i = 0; i < 3; i++)
            #pragma unroll
            for (int j = 0; j < 3; j++) {
                float id = (i == j) ? 1.f : 0.f;
                R[i][j] = id + f1 * K[i][j] + f2 * KK[i][j];
                V[i][j] = id + f2 * K[i][j] + f3 * KK[i][j];
            }
        float T0 = V[0][0]*v0 + V[0][1]*v1 + V[0][2]*v2;
        float T1 = V[1][0]*v0 + V[1][1]*v1 + V[1][2]*v2;
        float T2 = V[2][0]*v0 + V[2][1]*v1 + V[2][2]*v2;
        float px = pos[gg*3+0], py = pos[gg*3+1], pz = pos[gg*3+2];
        float dx = dir[gg*3+0], dy = dir[gg*3+1], dz = dir[gg*3+2];
        // M_rot = R^T : wp[i] = sum_j R[j][i]*p[j] + T[i]
        float wpx = R[0][0]*px + R[1][0]*py + R[2][0]*pz + T0;
        float wpy = R[0][1]*px + R[1][1]*py + R[2][1]*pz + T1;
        float wpz = R[0][2]*px + R[1][2]*py + R[2][2]*pz + T2;
        float wdx = R[0][0]*dx + R[1][0]*dy + R[2][0]*dz;
        float wdy = R[0][1]*dx + R[1][1]*dy + R[2][1]*dz;
        float wdz = R[0][2]*dx + R[1][2]*dy + R[2][2]*dz;
        wpx = (wpx != wpx) ? px : wpx;
        wpy = (wpy != wpy) ? py : wpy;
        wpz = (wpz != wpz) ? pz : wpz;
        wdx = (wdx != wdx) ? dx : wdx;
        wdy = (wdy != wdy) ? dy : wdy;
        wdz = (wdz != wdz) ? dz : wdz;
        out[gg*3+0] = wpx; out[gg*3+1] = wpy; out[gg*3+2] = wpz;
        float* o2 = out + (size_t)NROWS * 3;
        o2[gg*3+0] = wdx; o2[gg*3+1] = wdy; o2[gg*3+2] = wdz;
    }
}

// ---------------------------------------------------------------------------
extern "C" void kernel_launch(void* const* d_in, const int* in_sizes, int n_in,
                              void* d_out, int out_size, void* d_ws, size_t ws_size,
                              hipStream_t stream)
{
    const float* pos = (const float*)d_in[0];
    const float* dir = (const float*)d_in[1];
    const float* wc  = (const float*)d_in[2];
    const float* W0 = (const float*)d_in[3];  const float* b0 = (const float*)d_in[4];
    const float* W1 = (const float*)d_in[5];  const float* b1 = (const float*)d_in[6];
    const float* W2 = (const float*)d_in[7];  const float* b2 = (const float*)d_in[8];
    const float* W3 = (const float*)d_in[9];  const float* b3 = (const float*)d_in[10];
    const float* W4 = (const float*)d_in[11]; const float* b4 = (const float*)d_in[12];
    const float* W5 = (const float*)d_in[13]; const float* b5 = (const float*)d_in[14];
    const float* Wr = (const float*)d_in[15]; const float* br = (const float*)d_in[16];
    const float* Wv = (const float*)d_in[17]; const float* bv = (const float*)d_in[18];
    __bf16* pkb = (__bf16*)d_ws;
    float* out = (float*)d_out;

    pack_w<<<(PTOT + 255) / 256, 256, 0, stream>>>(W0, W1, W2, W3, W4, W5, Wr, Wv, pkb);
    se3_fused<<<NROWS / BROWS, 512, 0, stream>>>(pos, dir, wc,
                                                 b0, b1, b2, b3, b4, b5,
                                                 br, bv, pkb, out);
}

// Round 5
// 227.079 us; speedup vs baseline: 1.1236x; 1.1236x over previous
//
#include <hip/hip_runtime.h>
#include <hip/hip_bf16.h>
#include <math.h>

// ---------------------------------------------------------------------------
// SE3 warping field: nerf_encode -> 6-layer MLP (skip@4) -> heads -> se3 exp
// Round 5: occupancy-first. 512-thr blocks, 8 waves (m4 x n2), acc 2x4,
// minimal registers, launch_bounds(512,6) -> 3 blocks/CU = 24 waves/CU.
// Same proven pack/fragment/swizzle layouts as rounds 1-4.
// ---------------------------------------------------------------------------

typedef __bf16 bf16x8 __attribute__((ext_vector_type(8)));
typedef float  f32x4  __attribute__((ext_vector_type(4)));

#define NROWS 524288
#define BROWS 128

// packed-weight offsets in bf16 elements: frag layout [f][s][lane][j],
// value = W[m = 16f + (lane&15)][k = 32s + 8(lane>>4) + j]   (PROVEN r1-r4)
#define P0 0        // L0: K=64  (53 padded)
#define P1 8192     // L1: K=128
#define P2 24576
#define P3 40960
#define P4 57344    // L4: K=192 (53+pad11 | 128)
#define P5 81920
#define PH 98304    // head: m 0..2=Wv, 3..5=Wr, rest 0
#define PTOT 100352

// LDS byte offsets
#define X0_OFF   0        // [128][64 bf16] stride 128B (dead after L4)
#define XA_OFF   16384    // [128][128 bf16] stride 256B, in-place activations
#define BIAS_OFF 49152    // 800 floats: l*128+m for l=0..5, head at 768..799
#define SC_OFF   0        // screw [128][32B] (aliases X0; live after L5)
#define LDS_SZ   52352

// ---------------------------------------------------------------------------
template<int KS, int FAN>
__device__ __forceinline__ float pack_val(const float* __restrict__ W, int idx)
{
    int f  = idx / (KS * 512);
    int r2 = idx % (KS * 512);
    int s  = r2 >> 9, r3 = r2 & 511, ln = r3 >> 3, j = r3 & 7;
    int col = f * 16 + (ln & 15);
    int k   = s * 32 + (ln >> 4) * 8 + j;
    if (FAN == 128) return W[col * 128 + k];
    if (FAN == 53)  return (k < 53) ? W[col * 53 + k] : 0.f;
    if (k < 53)  return W[col * 181 + k];
    if (k < 64)  return 0.f;
    return W[col * 181 + (k - 11)];
}

__global__ void pack_w(const float* __restrict__ W0, const float* __restrict__ W1,
                       const float* __restrict__ W2, const float* __restrict__ W3,
                       const float* __restrict__ W4, const float* __restrict__ W5,
                       const float* __restrict__ Wr, const float* __restrict__ Wv,
                       __bf16* __restrict__ pk)
{
    int e = blockIdx.x * 256 + threadIdx.x;
    if (e >= PTOT) return;
    float val;
    if (e >= PH) {
        int rem = e - PH;
        int s = rem >> 9, r3 = rem & 511, ln = r3 >> 3, j = r3 & 7;
        int col = ln & 15;
        int k = s * 32 + (ln >> 4) * 8 + j;
        if (col < 3)      val = Wv[col * 128 + k];
        else if (col < 6) val = Wr[(col - 3) * 128 + k];
        else              val = 0.f;
    }
    else if (e < P1) val = pack_val<2, 53 >(W0, e - P0);
    else if (e < P2) val = pack_val<4, 128>(W1, e - P1);
    else if (e < P3) val = pack_val<4, 128>(W2, e - P2);
    else if (e < P4) val = pack_val<4, 128>(W3, e - P3);
    else if (e < P5) val = pack_val<6, 181>(W4, e - P4);
    else             val = pack_val<4, 128>(W5, e - P5);
    pk[e] = (__bf16)val;
}

// ---------------------------------------------------------------------------
__device__ __forceinline__ unsigned pack_bf16_2(float a, float b) {
    union { __bf16 h; unsigned short u; } x, y;
    x.h = (__bf16)a; y.h = (__bf16)b;
    return ((unsigned)y.u << 16) | (unsigned)x.u;
}

// One MLP layer. 8 waves: mfG = w&3 (4 col-groups of 32), nfG = w>>2
// (2 row-groups of 64). Wave computes D[m in 32mfG..+32)[rows 64nfG..+64):
// acc[mf<2][nf<4]. W read from global (L2-resident), B from LDS.
template<int KS, int SPLIT, bool BAR1>
__device__ __forceinline__ void mlp_layer(unsigned char* smem,
    const __bf16* __restrict__ pkL, int lyr,
    int lane, int c, int g, int mfG, int nfG)
{
    f32x4 acc[2][4];
    #pragma unroll
    for (int mf = 0; mf < 2; mf++) {
        f32x4 bb = *(const f32x4*)(smem + BIAS_OFF
                                   + (lyr * 128 + mfG * 32 + mf * 16 + g * 4) * 4);
        #pragma unroll
        for (int nf = 0; nf < 4; nf++) acc[mf][nf] = bb;
    }

    const bf16x8* pW = (const bf16x8*)pkL;
    bf16x8 Wf[2][2];
    #pragma unroll
    for (int mf = 0; mf < 2; mf++)
        Wf[0][mf] = pW[((mfG * 2 + mf) * KS + 0) * 64 + lane];

    #pragma unroll
    for (int s = 0; s < KS; s++) {
        if (s + 1 < KS) {
            #pragma unroll
            for (int mf = 0; mf < 2; mf++)
                Wf[(s + 1) & 1][mf] = pW[((mfG * 2 + mf) * KS + (s + 1)) * 64 + lane];
        }
        bf16x8 Bf[4];
        {
            int base, stride, k0;
            if (s < SPLIT) { base = X0_OFF; stride = 128; k0 = s * 32; }
            else           { base = XA_OFF; stride = 256; k0 = (s - SPLIT) * 32; }
            int bc = 2 * k0 + 16 * g;
            #pragma unroll
            for (int nf = 0; nf < 4; nf++) {
                int row = nfG * 64 + nf * 16 + c;
                Bf[nf] = *(const bf16x8*)(smem + base + row * stride
                                          + (bc ^ ((row & 7) << 4)));
            }
        }
        #pragma unroll
        for (int mf = 0; mf < 2; mf++)
            #pragma unroll
            for (int nf = 0; nf < 4; nf++)
                acc[mf][nf] = __builtin_amdgcn_mfma_f32_16x16x32_bf16(
                    Wf[s & 1][mf], Bf[nf], acc[mf][nf], 0, 0, 0);
    }

    if (BAR1) __syncthreads();   // all reads of XA complete before overwrite

    // ReLU + pack + store (D: col n=c, rows m' = 4g+r)
    #pragma unroll
    for (int mf = 0; mf < 2; mf++)
        #pragma unroll
        for (int nf = 0; nf < 4; nf++) {
            int row = nfG * 64 + nf * 16 + c;
            int bc  = 64 * mfG + 32 * mf + 8 * g;
            f32x4 a = acc[mf][nf];
            uint2 wv;
            wv.x = pack_bf16_2(fmaxf(a[0], 0.f), fmaxf(a[1], 0.f));
            wv.y = pack_bf16_2(fmaxf(a[2], 0.f), fmaxf(a[3], 0.f));
            *(uint2*)(smem + XA_OFF + row * 256 + (bc ^ ((row & 7) << 4))) = wv;
        }
    __syncthreads();
}

// ---------------------------------------------------------------------------
__global__ __launch_bounds__(512, 6)
void se3_fused(const float* __restrict__ pos, const float* __restrict__ dir,
               const float* __restrict__ wcode,
               const float* __restrict__ b0, const float* __restrict__ b1,
               const float* __restrict__ b2, const float* __restrict__ b3,
               const float* __restrict__ b4, const float* __restrict__ b5,
               const float* __restrict__ br, const float* __restrict__ bv,
               const __bf16* __restrict__ pk,
               float* __restrict__ out)
{
    __shared__ unsigned char smem[LDS_SZ];
    const int tid  = threadIdx.x;
    const int lane = tid & 63;
    const int w    = tid >> 6;
    const int c    = lane & 15;
    const int g    = lane >> 4;
    const int mfG  = w & 3;
    const int nfG  = w >> 2;
    const int r0   = blockIdx.x * BROWS;

    // ---- lower half: encode (2 threads per row, proven R3 code) ----
    if (tid < 256) {
        int row = tid >> 1, h = tid & 1;
        int gg = r0 + row;
        float p0 = pos[gg*3+0], p1 = pos[gg*3+1], p2 = pos[gg*3+2];
        float vals[32];
        if (h == 0) {
            #pragma unroll
            for (int j = 0; j < 21; j++) {          // sin cols 0..20
                float p = (j < 7) ? p0 : (j < 14 ? p1 : p2);
                float t = p * (float)(1 << (j % 7));
                t -= floorf(t);
                vals[j] = __sinf(6.283185307179586f * t);
            }
            #pragma unroll
            for (int j = 21; j < 32; j++) {         // cos idx 0..10 (cols 21..31)
                int idx = j - 21;
                float p = (idx < 7) ? p0 : (idx < 14 ? p1 : p2);
                float t = p * (float)(1 << (idx % 7));
                t -= floorf(t);
                vals[j] = __cosf(6.283185307179586f * t);
            }
        } else {
            #pragma unroll
            for (int j = 0; j < 10; j++) {          // cos idx 11..20 (cols 32..41)
                int idx = 11 + j;
                float p = (idx < 14) ? p1 : p2;
                float t = p * (float)(1 << (idx % 7));
                t -= floorf(t);
                vals[j] = __cosf(6.283185307179586f * t);
            }
            vals[10] = p0; vals[11] = p1; vals[12] = p2;   // cols 42..44
            const float4* wc4 = (const float4*)(wcode + (size_t)gg * 8);
            float4 wa = wc4[0], wb = wc4[1];
            vals[13] = wa.x; vals[14] = wa.y; vals[15] = wa.z; vals[16] = wa.w;
            vals[17] = wb.x; vals[18] = wb.y; vals[19] = wb.z; vals[20] = wb.w;
            #pragma unroll
            for (int j = 21; j < 32; j++) vals[j] = 0.f;   // cols 53..63
        }
        unsigned pkd[16];
        #pragma unroll
        for (int i = 0; i < 16; i++) pkd[i] = pack_bf16_2(vals[2*i], vals[2*i+1]);
        unsigned char* base = smem + X0_OFF + row * 128;
        int sw = (row & 7) << 4;
        #pragma unroll
        for (int cc = 0; cc < 4; cc++) {
            uint4 wv; wv.x = pkd[4*cc]; wv.y = pkd[4*cc+1];
            wv.z = pkd[4*cc+2]; wv.w = pkd[4*cc+3];
            *(uint4*)(base + ((64 * h + 16 * cc) ^ sw)) = wv;
        }
    } else {
        // ---- upper half: stage biases (runs concurrently with encode) ----
        for (int i = tid - 256; i < 800; i += 256) {
            float v;
            if (i < 768) {
                int l = i >> 7, m = i & 127;
                const float* bp = (l == 0) ? b0 : (l == 1) ? b1 : (l == 2) ? b2
                               : (l == 3) ? b3 : (l == 4) ? b4 : b5;
                v = bp[m];
            } else {
                int m = i - 768;
                v = (m < 3) ? bv[m] : ((m < 6) ? br[m - 3] : 0.f);
            }
            *(float*)(smem + BIAS_OFF + i * 4) = v;
        }
    }
    __syncthreads();

    // ---- MLP stem ----
    mlp_layer<2,2,false>(smem, pk + P0, 0, lane, c, g, mfG, nfG);
    mlp_layer<4,0,true >(smem, pk + P1, 1, lane, c, g, mfG, nfG);
    mlp_layer<4,0,true >(smem, pk + P2, 2, lane, c, g, mfG, nfG);
    mlp_layer<4,0,true >(smem, pk + P3, 3, lane, c, g, mfG, nfG);
    mlp_layer<6,2,true >(smem, pk + P4, 4, lane, c, g, mfG, nfG);  // skip from X0
    mlp_layer<4,0,true >(smem, pk + P5, 5, lane, c, g, mfG, nfG);

    // ---- head: screw = [v(3) | r(3)]; waves with mfG==0 (both nfG) ----
    if (mfG == 0) {
        const bf16x8* pW = (const bf16x8*)(pk + PH);
        f32x4 hb = *(const f32x4*)(smem + BIAS_OFF + (768 + g * 4) * 4);
        f32x4 hacc[4];
        #pragma unroll
        for (int nf = 0; nf < 4; nf++) hacc[nf] = hb;
        #pragma unroll
        for (int s = 0; s < 4; s++) {
            bf16x8 Wh = pW[s * 64 + lane];
            int bc = 64 * s + 16 * g;
            #pragma unroll
            for (int nf = 0; nf < 4; nf++) {
                int row = nfG * 64 + nf * 16 + c;
                bf16x8 B = *(const bf16x8*)(smem + XA_OFF + row * 256
                                            + (bc ^ ((row & 7) << 4)));
                hacc[nf] = __builtin_amdgcn_mfma_f32_16x16x32_bf16(Wh, B, hacc[nf], 0, 0, 0);
            }
        }
        // lane (c,g) holds m'=4g+r for row 64nfG+16nf+c (X0 dead -> SC)
        #pragma unroll
        for (int nf = 0; nf < 4; nf++) {
            int row = nfG * 64 + nf * 16 + c;
            if (g == 0) {
                *(f32x4*)(smem + SC_OFF + row * 32) = hacc[nf];         // v0..2, w0
            } else if (g == 1) {
                float* sp = (float*)(smem + SC_OFF + row * 32);
                sp[4] = hacc[nf][0];                                    // w1
                sp[5] = hacc[nf][1];                                    // w2
            }
        }
    }
    __syncthreads();

    // ---- se3 exp map epilogue (fp32, 1 thread per row) ----
    if (tid < BROWS) {
        int row = tid, gg = r0 + row;
        const float* sc = (const float*)(smem + SC_OFF + row * 32);
        float v0 = sc[0], v1 = sc[1], v2 = sc[2];
        float wx = sc[3], wy = sc[4], wz = sc[5];
        float ang2 = wx*wx + wy*wy + wz*wz;
        ang2 = fmaxf(ang2, 1e-4f);               // jnp.clip(.., eps)
        float ang = sqrtf(ang2);
        float sn = __sinf(ang), cs = __cosf(ang);
        float f1 = sn / ang;
        float f2 = (1.f - cs) / ang2;
        float f3 = (ang - sn) / (ang * ang2);
        float K[3][3] = {{0.f,  wz, -wy}, {-wz, 0.f,  wx}, { wy, -wx, 0.f}};
        float KK[3][3];
        #pragma unroll
        for (int i = 0; i < 3; i++)
            #pragma unroll
            for (int j = 0; j < 3; j++)
                KK[i][j] = K[i][0]*K[0][j] + K[i][1]*K[1][j] + K[i][2]*K[2][j];
        float R[3][3], V[3][3];
        #pragma unroll
        for (int i = 0; i < 3; i++)
            #pragma unroll
            for (int j = 0; j < 3; j++) {
                float id = (i == j) ? 1.f : 0.f;
                R[i][j] = id + f1 * K[i][j] + f2 * KK[i][j];
                V[i][j] = id + f2 * K[i][j] + f3 * KK[i][j];
            }
        float T0 = V[0][0]*v0 + V[0][1]*v1 + V[0][2]*v2;
        float T1 = V[1][0]*v0 + V[1][1]*v1 + V[1][2]*v2;
        float T2 = V[2][0]*v0 + V[2][1]*v1 + V[2][2]*v2;
        float px = pos[gg*3+0], py = pos[gg*3+1], pz = pos[gg*3+2];
        float dx = dir[gg*3+0], dy = dir[gg*3+1], dz = dir[gg*3+2];
        // M_rot = R^T : wp[i] = sum_j R[j][i]*p[j] + T[i]
        float wpx = R[0][0]*px + R[1][0]*py + R[2][0]*pz + T0;
        float wpy = R[0][1]*px + R[1][1]*py + R[2][1]*pz + T1;
        float wpz = R[0][2]*px + R[1][2]*py + R[2][2]*pz + T2;
        float wdx = R[0][0]*dx + R[1][0]*dy + R[2][0]*dz;
        float wdy = R[0][1]*dx + R[1][1]*dy + R[2][1]*dz;
        float wdz = R[0][2]*dx + R[1][2]*dy + R[2][2]*dz;
        wpx = (wpx != wpx) ? px : wpx;
        wpy = (wpy != wpy) ? py : wpy;
        wpz = (wpz != wpz) ? pz : wpz;
        wdx = (wdx != wdx) ? dx : wdx;
        wdy = (wdy != wdy) ? dy : wdy;
        wdz = (wdz != wdz) ? dz : wdz;
        out[gg*3+0] = wpx; out[gg*3+1] = wpy; out[gg*3+2] = wpz;
        float* o2 = out + (size_t)NROWS * 3;
        o2[gg*3+0] = wdx; o2[gg*3+1] = wdy; o2[gg*3+2] = wdz;
    }
}

// ---------------------------------------------------------------------------
extern "C" void kernel_launch(void* const* d_in, const int* in_sizes, int n_in,
                              void* d_out, int out_size, void* d_ws, size_t ws_size,
                              hipStream_t stream)
{
    const float* pos = (const float*)d_in[0];
    const float* dir = (const float*)d_in[1];
    const float* wc  = (const float*)d_in[2];
    const float* W0 = (const float*)d_in[3];  const float* b0 = (const float*)d_in[4];
    const float* W1 = (const float*)d_in[5];  const float* b1 = (const float*)d_in[6];
    const float* W2 = (const float*)d_in[7];  const float* b2 = (const float*)d_in[8];
    const float* W3 = (const float*)d_in[9];  const float* b3 = (const float*)d_in[10];
    const float* W4 = (const float*)d_in[11]; const float* b4 = (const float*)d_in[12];
    const float* W5 = (const float*)d_in[13]; const float* b5 = (const float*)d_in[14];
    const float* Wr = (const float*)d_in[15]; const float* br = (const float*)d_in[16];
    const float* Wv = (const float*)d_in[17]; const float* bv = (const float*)d_in[18];
    __bf16* pkb = (__bf16*)d_ws;
    float* out = (float*)d_out;

    pack_w<<<(PTOT + 255) / 256, 256, 0, stream>>>(W0, W1, W2, W3, W4, W5, Wr, Wv, pkb);
    se3_fused<<<NROWS / BROWS, 512, 0, stream>>>(pos, dir, wc,
                                                 b0, b1, b2, b3, b4, b5,
                                                 br, bv, pkb, out);
}